// Round 2
// baseline (11436.433 us; speedup 1.0000x reference)
//
#include <hip/hip_runtime.h>
#include <hip/hip_bf16.h>

typedef unsigned int u32;
typedef unsigned short u16;
typedef __attribute__((ext_vector_type(8))) short short8;
typedef __attribute__((ext_vector_type(4))) float floatx4;

#define L_SEQ 256
#define BATCH 64
#define DIM 1024

__device__ __forceinline__ float b2f(u16 u) {
  union { u32 i; float f; } v; v.i = ((u32)u) << 16; return v.f;
}
__device__ __forceinline__ u16 f2b(float f) {
  union { float f; u32 i; } v; v.f = f;
  u32 r = v.i + 0x7FFFu + ((v.i >> 16) & 1u);
  return (u16)(r >> 16);
}

__global__ void zero_cnt(u32* p) { p[threadIdx.x] = 0; }

// -------- weight convert+transpose: W[k][n] fp32 -> WT[n][k] bf16, 6 mats ---
__global__ __launch_bounds__(256) void transpose6(
    const float* __restrict__ w0, const float* __restrict__ w1,
    const float* __restrict__ w2, const float* __restrict__ w3,
    const float* __restrict__ w4, const float* __restrict__ w5,
    u16* __restrict__ wt)
{
  __shared__ u16 tile[64][66];
  const int z = blockIdx.z;
  const float* src = z==0?w0: z==1?w1: z==2?w2: z==3?w3: z==4?w4: w5;
  u16* dst = wt + (size_t)z * DIM * DIM;
  const int k0 = blockIdx.x * 64, n0 = blockIdx.y * 64;
  const int r = threadIdx.x & 63, q = threadIdx.x >> 6;
  #pragma unroll 4
  for (int rep = 0; rep < 16; ++rep) {
    int k = q * 16 + rep;
    tile[k][r] = f2b(src[(size_t)(k0 + k) * DIM + n0 + r]);
  }
  __syncthreads();
  #pragma unroll 4
  for (int rep = 0; rep < 16; ++rep) {
    int n = q * 16 + rep;
    dst[(size_t)(n0 + n) * DIM + k0 + r] = tile[r][n];
  }
}

// -------- embedding gather: fp32 emb -> bf16 X ------------------------------
__global__ __launch_bounds__(256) void embed_gather(
    const int* __restrict__ xs, const float* __restrict__ emb, u16* __restrict__ Xb)
{
  const int t = blockIdx.x * 256 + threadIdx.x;   // float4 chunk id
  const int row = t >> 8, ch = t & 255;           // 256 chunks per D-row
  const int tok = xs[row];
  float4 v = *(const float4*)(emb + (size_t)tok * DIM + ch * 4);
  union { ushort4 s; u16 u[4]; } o;
  o.u[0] = f2b(v.x); o.u[1] = f2b(v.y); o.u[2] = f2b(v.z); o.u[3] = f2b(v.w);
  *(ushort4*)(Xb + (size_t)row * DIM + ch * 4) = o.s;
}

// -------- input projections: Y = X @ W + b, bf16 MFMA, fp32 accum -----------
__global__ __launch_bounds__(256) void proj3(
    const u16* __restrict__ X, const u16* __restrict__ WTbase,
    const float* __restrict__ bi, const float* __restrict__ bfp,
    const float* __restrict__ bc,
    u16* __restrict__ XI, u16* __restrict__ XF, u16* __restrict__ XC)
{
  __shared__ __align__(16) u16 ldsA[8 * 64 * 8];
  __shared__ __align__(16) u16 ldsB[8 * 64 * 8];
  const int z = blockIdx.z;
  const u16* WT = WTbase + (size_t)z * DIM * DIM;     // [n][k] bf16
  const float* bias = z == 0 ? bi : (z == 1 ? bfp : bc);
  u16* Y = z == 0 ? XI : (z == 1 ? XF : XC);
  const int m0 = blockIdx.x * 128, n0 = blockIdx.y * 128;
  const int tid = threadIdx.x;
  const int l = tid & 63, w = tid >> 6;
  const int wm = w >> 1, wn = w & 1;

  floatx4 acc[4][4];
  #pragma unroll
  for (int i = 0; i < 4; ++i)
    #pragma unroll
    for (int j = 0; j < 4; ++j) acc[i][j] = (floatx4){0, 0, 0, 0};

  const int srow = tid >> 2, sch = tid & 3;    // staging row 0..63, k-chunk 0..3
  for (int k0 = 0; k0 < DIM; k0 += 32) {
    #pragma unroll
    for (int rr = 0; rr < 2; ++rr) {
      int row = rr * 64 + srow;
      uint4 va = *(const uint4*)(X  + (size_t)(m0 + row) * DIM + k0 + sch * 8);
      uint4 vb = *(const uint4*)(WT + (size_t)(n0 + row) * DIM + k0 + sch * 8);
      int slot = ((row >> 4) * 64 + (row & 15) + 16 * sch) * 8;  // frag order
      *(uint4*)(ldsA + slot) = va;
      *(uint4*)(ldsB + slot) = vb;
    }
    __syncthreads();
    short8 af[4], bf8[4];
    #pragma unroll
    for (int i = 0; i < 4; ++i) af[i]  = *(const short8*)(ldsA + ((wm * 4 + i) * 64 + l) * 8);
    #pragma unroll
    for (int j = 0; j < 4; ++j) bf8[j] = *(const short8*)(ldsB + ((wn * 4 + j) * 64 + l) * 8);
    #pragma unroll
    for (int i = 0; i < 4; ++i)
      #pragma unroll
      for (int j = 0; j < 4; ++j)
        acc[i][j] = __builtin_amdgcn_mfma_f32_16x16x32_bf16(af[i], bf8[j], acc[i][j], 0, 0, 0);
    __syncthreads();
  }
  const int lq = l >> 4, lc = l & 15;
  #pragma unroll
  for (int j = 0; j < 4; ++j) {
    int col = n0 + wn * 64 + j * 16 + lc;
    float bv = bias[col];
    #pragma unroll
    for (int i = 0; i < 4; ++i)
      #pragma unroll
      for (int r = 0; r < 4; ++r) {
        int row = m0 + wm * 64 + i * 16 + lq * 4 + r;
        Y[(size_t)row * DIM + col] = f2b(acc[i][j][r] + bv);
      }
  }
}

// -------- grid barrier (64 co-resident WGs, device-scope) -------------------
__device__ __forceinline__ void grid_barrier(u32* cnt, u32 target) {
  __syncthreads();
  if (threadIdx.x == 0) {
    __hip_atomic_fetch_add(cnt, 1u, __ATOMIC_RELEASE, __HIP_MEMORY_SCOPE_AGENT);
    while (__hip_atomic_load(cnt, __ATOMIC_ACQUIRE, __HIP_MEMORY_SCOPE_AGENT) < target) {
      __builtin_amdgcn_s_sleep(2);
    }
  }
  __syncthreads();
}

// -------- recurrent scan: 64 WGs, WG owns 16 output cols --------------------
__global__ __launch_bounds__(256, 1) void ran_scan_k(
    const float* __restrict__ Wic, const float* __restrict__ Wfc,
    const u16* __restrict__ XI, const u16* __restrict__ XF,
    const u16* __restrict__ XC,
    u16* __restrict__ Xb,        // bf16 x: residual in, h out (in-place)
    float* __restrict__ HoutF,   // fp32 h out (d_out; only last scan's survives)
    u16* __restrict__ cbf,       // double-buffered bf16 c: [2][64][1024]
    float* __restrict__ cf32,    // fp32 c carried between scans
    u32* __restrict__ cnt, int reverse, int load_c)
{
  __shared__ floatx4 part[4][4][2][64];   // [src wave][m-tile][gate][lane]
  const int tid = threadIdx.x, l = tid & 63, w = tid >> 6;
  const int d0 = blockIdx.x * 16;
  const int lq = l >> 4, lr = l & 15;
  const int eb = w * 16 + lq * 4;         // elementwise batch-row base
  const int ed = d0 + lr;                 // elementwise column

  // B fragments in registers: wave w covers k in [w*256,(w+1)*256)
  short8 bregs[8][2];
  for (int kk8 = 0; kk8 < 8; ++kk8) {
    const int kbase = (w * 8 + kk8) * 32 + lq * 8;
    #pragma unroll
    for (int g = 0; g < 2; ++g) {
      const float* W = g ? Wfc : Wic;
      union { short8 v; u16 u[8]; } tmp;
      #pragma unroll
      for (int j = 0; j < 8; ++j)
        tmp.u[j] = f2b(W[(size_t)(kbase + j) * DIM + ed]);
      bregs[kk8][g] = tmp.v;
    }
  }

  float creg[4];
  #pragma unroll
  for (int r = 0; r < 4; ++r)
    creg[r] = load_c ? cf32[(size_t)(eb + r) * DIM + ed] : 0.0f;
  #pragma unroll
  for (int r = 0; r < 4; ++r)
    cbf[(size_t)(eb + r) * DIM + ed] = f2b(creg[r]);   // buffer 0

  u32 epoch = 1;
  grid_barrier(cnt, 64u * epoch); ++epoch;

  int t = reverse ? (L_SEQ - 1) : 0;
  const int dt = reverse ? -1 : 1;
  for (int step = 0; step < L_SEQ; ++step, t += dt) {
    const size_t base = (size_t)t * (BATCH * DIM);
    float xi[4], xf[4], xc[4], xv[4];
    #pragma unroll
    for (int r = 0; r < 4; ++r) {
      const size_t idx = base + (size_t)(eb + r) * DIM + ed;
      xi[r] = b2f(XI[idx]); xf[r] = b2f(XF[idx]);
      xc[r] = b2f(XC[idx]); xv[r] = b2f(Xb[idx]);
    }
    const u16* crd = cbf + (size_t)(step & 1) * (BATCH * DIM);
    u16* cwr = cbf + (size_t)((step + 1) & 1) * (BATCH * DIM);

    floatx4 accI[4], accF[4];
    #pragma unroll
    for (int mt = 0; mt < 4; ++mt) { accI[mt] = (floatx4){0,0,0,0}; accF[mt] = (floatx4){0,0,0,0}; }
    #pragma unroll
    for (int kk8 = 0; kk8 < 8; ++kk8) {
      const int kcol = (w * 8 + kk8) * 32 + lq * 8;
      #pragma unroll
      for (int mt = 0; mt < 4; ++mt) {
        const short8 a = __builtin_bit_cast(short8,
            *(const uint4*)(crd + (size_t)(mt * 16 + lr) * DIM + kcol));
        accI[mt] = __builtin_amdgcn_mfma_f32_16x16x32_bf16(a, bregs[kk8][0], accI[mt], 0, 0, 0);
        accF[mt] = __builtin_amdgcn_mfma_f32_16x16x32_bf16(a, bregs[kk8][1], accF[mt], 0, 0, 0);
      }
    }
    // cross-wave K reduction through LDS
    #pragma unroll
    for (int mt = 0; mt < 4; ++mt) {
      part[w][mt][0][l] = accI[mt];
      part[w][mt][1][l] = accF[mt];
    }
    __syncthreads();
    floatx4 sI = part[0][w][0][l], sF = part[0][w][1][l];
    #pragma unroll
    for (int pw = 1; pw < 4; ++pw) { sI += part[pw][w][0][l]; sF += part[pw][w][1][l]; }

    #pragma unroll
    for (int r = 0; r < 4; ++r) {
      const float iv = 1.0f / (1.0f + __expf(-(xi[r] + sI[r])));
      const float fv = 1.0f / (1.0f + __expf(-(xf[r] + sF[r])));
      const float cn = iv * xc[r] + fv * creg[r];
      creg[r] = cn;
      const float hv = tanhf(cn) + xv[r];
      const size_t idx = base + (size_t)(eb + r) * DIM + ed;
      Xb[idx] = f2b(hv);
      HoutF[idx] = hv;
      cwr[(size_t)(eb + r) * DIM + ed] = f2b(cn);
    }
    grid_barrier(cnt, 64u * epoch); ++epoch;
  }
  #pragma unroll
  for (int r = 0; r < 4; ++r)
    cf32[(size_t)(eb + r) * DIM + ed] = creg[r];
}

// -------- launcher ----------------------------------------------------------
extern "C" void kernel_launch(void* const* d_in, const int* in_sizes, int n_in,
                              void* d_out, int out_size, void* d_ws, size_t ws_size,
                              hipStream_t stream) {
  (void)in_sizes; (void)out_size; (void)ws_size;
  const int* xs = (const int*)d_in[0];
  const float* emb = (const float*)d_in[1];
  const float* W[18];
  for (int i = 0; i < 18 && i < n_in; ++i) W[i] = (const float*)d_in[i];

  char* ws = (char*)d_ws;
  u32* cnt    = (u32*)ws;                            // 256 B counters
  u16* WT     = (u16*)(ws + 256);                    // 6 x [1024][1024] bf16 (transposed x-weights)
  u16* Xb     = (u16*)(ws + 12583168ull);            // [256][64][1024] bf16, updated in place
  u16* XIb    = (u16*)(ws + 46137600ull);            // bf16 projections
  u16* XFb    = (u16*)(ws + 79692032ull);
  u16* XCb    = (u16*)(ws + 113246464ull);
  u16* cbf    = (u16*)(ws + 146800896ull);           // [2][64][1024] bf16
  float* cf32 = (float*)(ws + 147063040ull);         // [64][1024] fp32

  zero_cnt<<<1, 64, 0, stream>>>(cnt);
  transpose6<<<dim3(16, 16, 6), 256, 0, stream>>>(W[2], W[4], W[6], W[10], W[12], W[14], WT);
  embed_gather<<<16384, 256, 0, stream>>>(xs, emb, Xb);

  for (int s = 0; s < 4; ++s) {
    const int p = s & 1;   // 0 = forward(fw weights), 1 = reverse(bw weights)
    const u16* WTs = WT + (size_t)p * 3 * DIM * DIM;
    proj3<<<dim3(128, 8, 3), 256, 0, stream>>>(
        Xb, WTs, W[p ? 15 : 7], W[p ? 16 : 8], W[p ? 17 : 9], XIb, XFb, XCb);
    ran_scan_k<<<64, 256, 0, stream>>>(
        W[p ? 11 : 3], W[p ? 13 : 5], XIb, XFb, XCb, Xb, (float*)d_out,
        cbf, cf32, cnt + s * 16, p, s > 0 ? 1 : 0);
  }
}

// Round 3
// 10830.074 us; speedup vs baseline: 1.0560x; 1.0560x over previous
//
#include <hip/hip_runtime.h>
#include <hip/hip_bf16.h>

typedef unsigned int u32;
typedef unsigned short u16;
typedef __attribute__((ext_vector_type(8))) short short8;
typedef __attribute__((ext_vector_type(4))) float floatx4;

#define L_SEQ 256
#define BATCH 64
#define DIM 1024

__device__ __forceinline__ float b2f(u16 u) {
  union { u32 i; float f; } v; v.i = ((u32)u) << 16; return v.f;
}
__device__ __forceinline__ u16 f2b(float f) {
  union { float f; u32 i; } v; v.f = f;
  u32 r = v.i + 0x7FFFu + ((v.i >> 16) & 1u);
  return (u16)(r >> 16);
}

__global__ void zero_cnt(u32* p) { p[threadIdx.x] = 0; }

// -------- weight convert+transpose: W[k][n] fp32 -> WT[n][k] bf16, 6 mats ---
__global__ __launch_bounds__(256) void transpose6(
    const float* __restrict__ w0, const float* __restrict__ w1,
    const float* __restrict__ w2, const float* __restrict__ w3,
    const float* __restrict__ w4, const float* __restrict__ w5,
    u16* __restrict__ wt)
{
  __shared__ u16 tile[64][66];
  const int z = blockIdx.z;
  const float* src = z==0?w0: z==1?w1: z==2?w2: z==3?w3: z==4?w4: w5;
  u16* dst = wt + (size_t)z * DIM * DIM;
  const int k0 = blockIdx.x * 64, n0 = blockIdx.y * 64;
  const int r = threadIdx.x & 63, q = threadIdx.x >> 6;
  #pragma unroll 4
  for (int rep = 0; rep < 16; ++rep) {
    int k = q * 16 + rep;
    tile[k][r] = f2b(src[(size_t)(k0 + k) * DIM + n0 + r]);
  }
  __syncthreads();
  #pragma unroll 4
  for (int rep = 0; rep < 16; ++rep) {
    int n = q * 16 + rep;
    dst[(size_t)(n0 + n) * DIM + k0 + r] = tile[r][n];
  }
}

// -------- embedding gather: fp32 emb -> bf16 X ------------------------------
__global__ __launch_bounds__(256) void embed_gather(
    const int* __restrict__ xs, const float* __restrict__ emb, u16* __restrict__ Xb)
{
  const int t = blockIdx.x * 256 + threadIdx.x;   // float4 chunk id
  const int row = t >> 8, ch = t & 255;           // 256 chunks per D-row
  const int tok = xs[row];
  float4 v = *(const float4*)(emb + (size_t)tok * DIM + ch * 4);
  union { ushort4 s; u16 u[4]; } o;
  o.u[0] = f2b(v.x); o.u[1] = f2b(v.y); o.u[2] = f2b(v.z); o.u[3] = f2b(v.w);
  *(ushort4*)(Xb + (size_t)row * DIM + ch * 4) = o.s;
}

// -------- input projections: Y = X @ W + b, bf16 MFMA, fp32 accum -----------
__global__ __launch_bounds__(256) void proj3(
    const u16* __restrict__ X, const u16* __restrict__ WTbase,
    const float* __restrict__ bi, const float* __restrict__ bfp,
    const float* __restrict__ bc,
    u16* __restrict__ XI, u16* __restrict__ XF, u16* __restrict__ XC)
{
  __shared__ __align__(16) u16 ldsA[8 * 64 * 8];
  __shared__ __align__(16) u16 ldsB[8 * 64 * 8];
  const int z = blockIdx.z;
  const u16* WT = WTbase + (size_t)z * DIM * DIM;     // [n][k] bf16
  const float* bias = z == 0 ? bi : (z == 1 ? bfp : bc);
  u16* Y = z == 0 ? XI : (z == 1 ? XF : XC);
  const int m0 = blockIdx.x * 128, n0 = blockIdx.y * 128;
  const int tid = threadIdx.x;
  const int l = tid & 63, w = tid >> 6;
  const int wm = w >> 1, wn = w & 1;

  floatx4 acc[4][4];
  #pragma unroll
  for (int i = 0; i < 4; ++i)
    #pragma unroll
    for (int j = 0; j < 4; ++j) acc[i][j] = (floatx4){0, 0, 0, 0};

  const int srow = tid >> 2, sch = tid & 3;    // staging row 0..63, k-chunk 0..3
  for (int k0 = 0; k0 < DIM; k0 += 32) {
    #pragma unroll
    for (int rr = 0; rr < 2; ++rr) {
      int row = rr * 64 + srow;
      uint4 va = *(const uint4*)(X  + (size_t)(m0 + row) * DIM + k0 + sch * 8);
      uint4 vb = *(const uint4*)(WT + (size_t)(n0 + row) * DIM + k0 + sch * 8);
      int slot = ((row >> 4) * 64 + (row & 15) + 16 * sch) * 8;  // frag order
      *(uint4*)(ldsA + slot) = va;
      *(uint4*)(ldsB + slot) = vb;
    }
    __syncthreads();
    short8 af[4], bf8[4];
    #pragma unroll
    for (int i = 0; i < 4; ++i) af[i]  = *(const short8*)(ldsA + ((wm * 4 + i) * 64 + l) * 8);
    #pragma unroll
    for (int j = 0; j < 4; ++j) bf8[j] = *(const short8*)(ldsB + ((wn * 4 + j) * 64 + l) * 8);
    #pragma unroll
    for (int i = 0; i < 4; ++i)
      #pragma unroll
      for (int j = 0; j < 4; ++j)
        acc[i][j] = __builtin_amdgcn_mfma_f32_16x16x32_bf16(af[i], bf8[j], acc[i][j], 0, 0, 0);
    __syncthreads();
  }
  const int lq = l >> 4, lc = l & 15;
  #pragma unroll
  for (int j = 0; j < 4; ++j) {
    int col = n0 + wn * 64 + j * 16 + lc;
    float bv = bias[col];
    #pragma unroll
    for (int i = 0; i < 4; ++i)
      #pragma unroll
      for (int r = 0; r < 4; ++r) {
        int row = m0 + wm * 64 + i * 16 + lq * 4 + r;
        Y[(size_t)row * DIM + col] = f2b(acc[i][j][r] + bv);
      }
  }
}

// -------- split grid barrier (64 co-resident WGs, device scope) -------------
// arrive: publish this WG's stores (release add, small dirty set thanks to NT
//         stores elsewhere), non-blocking.
// wait:   RELAXED spin (no per-poll invalidate), ONE acquire fence on exit.
__device__ __forceinline__ void barrier_arrive(u32* cnt) {
  __syncthreads();   // drains each wave's outstanding stores (vmcnt) first
  if (threadIdx.x == 0)
    __hip_atomic_fetch_add(cnt, 1u, __ATOMIC_RELEASE, __HIP_MEMORY_SCOPE_AGENT);
}
__device__ __forceinline__ void barrier_wait(u32* cnt, u32 target) {
  if (threadIdx.x == 0) {
    while (__hip_atomic_load(cnt, __ATOMIC_RELAXED, __HIP_MEMORY_SCOPE_AGENT) < target)
      __builtin_amdgcn_s_sleep(2);
    __builtin_amdgcn_fence(__ATOMIC_ACQUIRE, "agent");
  }
  __syncthreads();
}

// -------- recurrent scan: 64 WGs, WG owns 16 output cols --------------------
__global__ __launch_bounds__(256, 1) void ran_scan_k(
    const float* __restrict__ Wic, const float* __restrict__ Wfc,
    const u16* __restrict__ XI, const u16* __restrict__ XF,
    const u16* __restrict__ XC,
    u16* __restrict__ Xb,        // bf16 x: residual in, h out (in-place, NT)
    float* __restrict__ HoutF,   // fp32 h out (d_out; written only when write_out)
    u16* __restrict__ cbf,       // double-buffered bf16 c: [2][64][1024]
    float* __restrict__ cf32,    // fp32 c carried between scans
    u32* __restrict__ cnt, int reverse, int load_c, int write_out)
{
  __shared__ floatx4 part[4][4][2][64];   // [src wave][m-tile][gate][lane]
  const int tid = threadIdx.x, l = tid & 63, w = tid >> 6;
  const int d0 = blockIdx.x * 16;
  const int lq = l >> 4, lr = l & 15;
  const int eb = w * 16 + lq * 4;         // elementwise batch-row base
  const int ed = d0 + lr;                 // elementwise column

  // B fragments in registers: wave w covers k in [w*256,(w+1)*256)
  short8 bregs[8][2];
  for (int kk8 = 0; kk8 < 8; ++kk8) {
    const int kbase = (w * 8 + kk8) * 32 + lq * 8;
    #pragma unroll
    for (int g = 0; g < 2; ++g) {
      const float* W = g ? Wfc : Wic;
      union { short8 v; u16 u[8]; } tmp;
      #pragma unroll
      for (int j = 0; j < 8; ++j)
        tmp.u[j] = f2b(W[(size_t)(kbase + j) * DIM + ed]);
      bregs[kk8][g] = tmp.v;
    }
  }

  float creg[4];
  #pragma unroll
  for (int r = 0; r < 4; ++r)
    creg[r] = load_c ? cf32[(size_t)(eb + r) * DIM + ed] : 0.0f;
  #pragma unroll
  for (int r = 0; r < 4; ++r)
    cbf[(size_t)(eb + r) * DIM + ed] = f2b(creg[r]);   // buffer 0 (plain store)

  int t = reverse ? (L_SEQ - 1) : 0;
  const int dt = reverse ? -1 : 1;

  // prefetch step-0 gates into registers (independent of c)
  float xi[4], xf[4], xc[4], xv[4];
  {
    const size_t base = (size_t)t * (BATCH * DIM);
    #pragma unroll
    for (int r = 0; r < 4; ++r) {
      const size_t idx = base + (size_t)(eb + r) * DIM + ed;
      xi[r] = b2f(XI[idx]); xf[r] = b2f(XF[idx]);
      xc[r] = b2f(XC[idx]); xv[r] = b2f(Xb[idx]);
    }
  }

  u32 epoch = 1;
  barrier_arrive(cnt);
  barrier_wait(cnt, 64u * epoch); ++epoch;

  for (int step = 0; step < L_SEQ; ++step, t += dt) {
    const size_t base = (size_t)t * (BATCH * DIM);
    const u16* crd = cbf + (size_t)(step & 1) * (BATCH * DIM);
    u16* cwr = cbf + (size_t)((step + 1) & 1) * (BATCH * DIM);

    floatx4 accI[4], accF[4];
    #pragma unroll
    for (int mt = 0; mt < 4; ++mt) { accI[mt] = (floatx4){0,0,0,0}; accF[mt] = (floatx4){0,0,0,0}; }
    #pragma unroll
    for (int kk8 = 0; kk8 < 8; ++kk8) {
      const int kcol = (w * 8 + kk8) * 32 + lq * 8;
      #pragma unroll
      for (int mt = 0; mt < 4; ++mt) {
        const short8 a = __builtin_bit_cast(short8,
            *(const uint4*)(crd + (size_t)(mt * 16 + lr) * DIM + kcol));
        accI[mt] = __builtin_amdgcn_mfma_f32_16x16x32_bf16(a, bregs[kk8][0], accI[mt], 0, 0, 0);
        accF[mt] = __builtin_amdgcn_mfma_f32_16x16x32_bf16(a, bregs[kk8][1], accF[mt], 0, 0, 0);
      }
    }
    // cross-wave K reduction through LDS
    #pragma unroll
    for (int mt = 0; mt < 4; ++mt) {
      part[w][mt][0][l] = accI[mt];
      part[w][mt][1][l] = accF[mt];
    }
    __syncthreads();
    floatx4 sI = part[0][w][0][l], sF = part[0][w][1][l];
    #pragma unroll
    for (int pw = 1; pw < 4; ++pw) { sI += part[pw][w][0][l]; sF += part[pw][w][1][l]; }

    #pragma unroll
    for (int r = 0; r < 4; ++r) {
      const float iv = 1.0f / (1.0f + __expf(-(xi[r] + sI[r])));
      const float fv = 1.0f / (1.0f + __expf(-(xf[r] + sF[r])));
      const float cn = iv * xc[r] + fv * creg[r];
      creg[r] = cn;
      const float hv = tanhf(cn) + xv[r];
      const size_t idx = base + (size_t)(eb + r) * DIM + ed;
      __builtin_nontemporal_store(f2b(hv), Xb + idx);      // NT: no L2 dirty
      if (write_out) __builtin_nontemporal_store(hv, HoutF + idx);
      cwr[(size_t)(eb + r) * DIM + ed] = f2b(cn);          // plain: flushed by release
    }
    barrier_arrive(cnt);
    // prefetch next step's gates while other WGs catch up (hidden latency)
    if (step + 1 < L_SEQ) {
      const size_t nb = (size_t)(t + dt) * (BATCH * DIM);
      #pragma unroll
      for (int r = 0; r < 4; ++r) {
        const size_t idx = nb + (size_t)(eb + r) * DIM + ed;
        xi[r] = b2f(XI[idx]); xf[r] = b2f(XF[idx]);
        xc[r] = b2f(XC[idx]); xv[r] = b2f(Xb[idx]);
      }
    }
    barrier_wait(cnt, 64u * epoch); ++epoch;
  }
  #pragma unroll
  for (int r = 0; r < 4; ++r)
    cf32[(size_t)(eb + r) * DIM + ed] = creg[r];
}

// -------- launcher ----------------------------------------------------------
extern "C" void kernel_launch(void* const* d_in, const int* in_sizes, int n_in,
                              void* d_out, int out_size, void* d_ws, size_t ws_size,
                              hipStream_t stream) {
  (void)in_sizes; (void)out_size; (void)ws_size;
  const int* xs = (const int*)d_in[0];
  const float* emb = (const float*)d_in[1];
  const float* W[18];
  for (int i = 0; i < 18 && i < n_in; ++i) W[i] = (const float*)d_in[i];

  char* ws = (char*)d_ws;
  u32* cnt    = (u32*)ws;                            // 256 B counters
  u16* WT     = (u16*)(ws + 256);                    // 6 x [1024][1024] bf16 (transposed x-weights)
  u16* Xb     = (u16*)(ws + 12583168ull);            // [256][64][1024] bf16, updated in place
  u16* XIb    = (u16*)(ws + 46137600ull);            // bf16 projections
  u16* XFb    = (u16*)(ws + 79692032ull);
  u16* XCb    = (u16*)(ws + 113246464ull);
  u16* cbf    = (u16*)(ws + 146800896ull);           // [2][64][1024] bf16
  float* cf32 = (float*)(ws + 147063040ull);         // [64][1024] fp32

  zero_cnt<<<1, 64, 0, stream>>>(cnt);
  transpose6<<<dim3(16, 16, 6), 256, 0, stream>>>(W[2], W[4], W[6], W[10], W[12], W[14], WT);
  embed_gather<<<16384, 256, 0, stream>>>(xs, emb, Xb);

  for (int s = 0; s < 4; ++s) {
    const int p = s & 1;   // 0 = forward(fw weights), 1 = reverse(bw weights)
    const u16* WTs = WT + (size_t)p * 3 * DIM * DIM;
    proj3<<<dim3(128, 8, 3), 256, 0, stream>>>(
        Xb, WTs, W[p ? 15 : 7], W[p ? 16 : 8], W[p ? 17 : 9], XIb, XFb, XCb);
    ran_scan_k<<<64, 256, 0, stream>>>(
        W[p ? 11 : 3], W[p ? 13 : 5], XIb, XFb, XCb, Xb, (float*)d_out,
        cbf, cf32, cnt + s * 16, p, s > 0 ? 1 : 0, s == 3 ? 1 : 0);
  }
}

// Round 4
// 4701.805 us; speedup vs baseline: 2.4323x; 2.3034x over previous
//
#include <hip/hip_runtime.h>
#include <hip/hip_bf16.h>

typedef unsigned int u32;
typedef unsigned short u16;
typedef unsigned long long u64;
typedef __attribute__((ext_vector_type(8))) short short8;
typedef __attribute__((ext_vector_type(4))) float floatx4;

#define L_SEQ 256
#define BATCH 64
#define DIM 1024
#define GROUPS 8      // independent batch groups (8 rows each)
#define GWGS 32       // WGs per group, each owns 32 d-cols
#define GROWS 8       // batch rows per group

__device__ __forceinline__ float b2f(u16 u) {
  union { u32 i; float f; } v; v.i = ((u32)u) << 16; return v.f;
}
__device__ __forceinline__ u16 f2b(float f) {
  union { float f; u32 i; } v; v.f = f;
  u32 r = v.i + 0x7FFFu + ((v.i >> 16) & 1u);
  return (u16)(r >> 16);
}

// LLC-coherent (device-visible, cache-bypassing) 2-byte store
__device__ __forceinline__ void st_b16_sc(const u16* p, u16 v) {
  asm volatile("global_store_short %0, %1, off sc0 sc1"
               :: "v"((u64)(uintptr_t)p), "v"((u32)v) : "memory");
}

__global__ void zero_cnt(u32* p) {
  #pragma unroll
  for (int i = 0; i < 4; ++i) p[threadIdx.x * 4 + i] = 0;
}

// -------- weight convert+transpose: W[k][n] fp32 -> WT[n][k] bf16, 6 mats ---
__global__ __launch_bounds__(256) void transpose6(
    const float* __restrict__ w0, const float* __restrict__ w1,
    const float* __restrict__ w2, const float* __restrict__ w3,
    const float* __restrict__ w4, const float* __restrict__ w5,
    u16* __restrict__ wt)
{
  __shared__ u16 tile[64][66];
  const int z = blockIdx.z;
  const float* src = z==0?w0: z==1?w1: z==2?w2: z==3?w3: z==4?w4: w5;
  u16* dst = wt + (size_t)z * DIM * DIM;
  const int k0 = blockIdx.x * 64, n0 = blockIdx.y * 64;
  const int r = threadIdx.x & 63, q = threadIdx.x >> 6;
  #pragma unroll 4
  for (int rep = 0; rep < 16; ++rep) {
    int k = q * 16 + rep;
    tile[k][r] = f2b(src[(size_t)(k0 + k) * DIM + n0 + r]);
  }
  __syncthreads();
  #pragma unroll 4
  for (int rep = 0; rep < 16; ++rep) {
    int n = q * 16 + rep;
    dst[(size_t)(n0 + n) * DIM + k0 + r] = tile[r][n];
  }
}

// -------- embedding gather: fp32 emb -> bf16 X ------------------------------
__global__ __launch_bounds__(256) void embed_gather(
    const int* __restrict__ xs, const float* __restrict__ emb, u16* __restrict__ Xb)
{
  const int t = blockIdx.x * 256 + threadIdx.x;
  const int row = t >> 8, ch = t & 255;
  const int tok = xs[row];
  float4 v = *(const float4*)(emb + (size_t)tok * DIM + ch * 4);
  union { ushort4 s; u16 u[4]; } o;
  o.u[0] = f2b(v.x); o.u[1] = f2b(v.y); o.u[2] = f2b(v.z); o.u[3] = f2b(v.w);
  *(ushort4*)(Xb + (size_t)row * DIM + ch * 4) = o.s;
}

// -------- input projections: Y = X @ W + b, bf16 MFMA, fp32 accum -----------
__global__ __launch_bounds__(256) void proj3(
    const u16* __restrict__ X, const u16* __restrict__ WTbase,
    const float* __restrict__ bi, const float* __restrict__ bfp,
    const float* __restrict__ bc,
    u16* __restrict__ XI, u16* __restrict__ XF, u16* __restrict__ XC)
{
  __shared__ __align__(16) u16 ldsA[8 * 64 * 8];
  __shared__ __align__(16) u16 ldsB[8 * 64 * 8];
  const int z = blockIdx.z;
  const u16* WT = WTbase + (size_t)z * DIM * DIM;
  const float* bias = z == 0 ? bi : (z == 1 ? bfp : bc);
  u16* Y = z == 0 ? XI : (z == 1 ? XF : XC);
  const int m0 = blockIdx.x * 128, n0 = blockIdx.y * 128;
  const int tid = threadIdx.x;
  const int l = tid & 63, w = tid >> 6;
  const int wm = w >> 1, wn = w & 1;

  floatx4 acc[4][4];
  #pragma unroll
  for (int i = 0; i < 4; ++i)
    #pragma unroll
    for (int j = 0; j < 4; ++j) acc[i][j] = (floatx4){0, 0, 0, 0};

  const int srow = tid >> 2, sch = tid & 3;
  for (int k0 = 0; k0 < DIM; k0 += 32) {
    #pragma unroll
    for (int rr = 0; rr < 2; ++rr) {
      int row = rr * 64 + srow;
      uint4 va = *(const uint4*)(X  + (size_t)(m0 + row) * DIM + k0 + sch * 8);
      uint4 vb = *(const uint4*)(WT + (size_t)(n0 + row) * DIM + k0 + sch * 8);
      int slot = ((row >> 4) * 64 + (row & 15) + 16 * sch) * 8;
      *(uint4*)(ldsA + slot) = va;
      *(uint4*)(ldsB + slot) = vb;
    }
    __syncthreads();
    short8 af[4], bf8[4];
    #pragma unroll
    for (int i = 0; i < 4; ++i) af[i]  = *(const short8*)(ldsA + ((wm * 4 + i) * 64 + l) * 8);
    #pragma unroll
    for (int j = 0; j < 4; ++j) bf8[j] = *(const short8*)(ldsB + ((wn * 4 + j) * 64 + l) * 8);
    #pragma unroll
    for (int i = 0; i < 4; ++i)
      #pragma unroll
      for (int j = 0; j < 4; ++j)
        acc[i][j] = __builtin_amdgcn_mfma_f32_16x16x32_bf16(af[i], bf8[j], acc[i][j], 0, 0, 0);
    __syncthreads();
  }
  const int lq = l >> 4, lc = l & 15;
  #pragma unroll
  for (int j = 0; j < 4; ++j) {
    int col = n0 + wn * 64 + j * 16 + lc;
    float bv = bias[col];
    #pragma unroll
    for (int i = 0; i < 4; ++i)
      #pragma unroll
      for (int r = 0; r < 4; ++r) {
        int row = m0 + wm * 64 + i * 16 + lq * 4 + r;
        Y[(size_t)row * DIM + col] = f2b(acc[i][j][r] + bv);
      }
  }
}

// -------- group barrier: relaxed atomics only, no cache fences --------------
__device__ __forceinline__ void g_arrive(u32* c) {
  __syncthreads();   // per-wave vmcnt(0): all sc1 stores complete (at LLC) first
  if (threadIdx.x == 0)
    __hip_atomic_fetch_add(c, 1u, __ATOMIC_RELAXED, __HIP_MEMORY_SCOPE_AGENT);
}
__device__ __forceinline__ void g_wait(u32* c, u32 tgt) {
  if (threadIdx.x == 0)
    while (__hip_atomic_load(c, __ATOMIC_RELAXED, __HIP_MEMORY_SCOPE_AGENT) < tgt)
      __builtin_amdgcn_s_sleep(1);
  __syncthreads();
}

// -------- recurrent scan: 8 independent groups x 32 WGs ---------------------
// group owns batch rows [g*8, g*8+8); WG owns d-cols [member*32, member*32+32)
__global__ __launch_bounds__(256, 1) void ran_scan_g(
    const float* __restrict__ Wic, const float* __restrict__ Wfc,
    const u16* __restrict__ XI, const u16* __restrict__ XF,
    const u16* __restrict__ XC,
    u16* __restrict__ Xb,        // bf16 x: residual in, h out (in-place, NT)
    float* __restrict__ HoutF,   // fp32 h out (only when write_out)
    u16* __restrict__ cbf,       // per-group dbuf bf16 c: [8][2][8][1024]
    float* __restrict__ cf32,    // fp32 c carried between scans
    u32* __restrict__ cnt,       // per-scan region; group line at +g*32
    int reverse, int load_c, int write_out)
{
  __shared__ floatx4 part[4][2][2][64];   // [k-wave][n-tile][gate][lane]
  const int tid = threadIdx.x, l = tid & 63, w = tid >> 6;
  const int group = blockIdx.x & 7, member = blockIdx.x >> 3;
  const int q = l >> 4, lr = l & 15;
  const int d0 = member * 32;
  const int g8 = group * GROWS;
  u16* cgrp = cbf + (size_t)group * (2 * GROWS * DIM);
  u32* gcnt = cnt + group * 32;
  const int act = (w == 0) && (q < 2);    // lanes doing elementwise (rows q*4..q*4+3)
  const int mrow = q * 4;

  // B fragments in VGPRs: [kk8][n-tile][mat]; wave w covers k in [w*256,(w+1)*256)
  short8 bregs[8][2][2];
  for (int kk8 = 0; kk8 < 8; ++kk8) {
    const int kbase = w * 256 + kk8 * 32 + q * 8;
    #pragma unroll
    for (int nt = 0; nt < 2; ++nt) {
      const int n = d0 + nt * 16 + lr;
      #pragma unroll
      for (int g = 0; g < 2; ++g) {
        const float* W = g ? Wfc : Wic;
        union { short8 v; u16 u[8]; } tmp;
        #pragma unroll
        for (int j = 0; j < 8; ++j) tmp.u[j] = f2b(W[(size_t)(kbase + j) * DIM + n]);
        bregs[kk8][nt][g] = tmp.v;
      }
    }
  }

  float creg[2][4];
  float xi[2][4], xf[2][4], xc[2][4], xv[2][4];
  int t = reverse ? (L_SEQ - 1) : 0;
  const int dt = reverse ? -1 : 1;

  if (act) {
    #pragma unroll
    for (int nt = 0; nt < 2; ++nt)
      #pragma unroll
      for (int r = 0; r < 4; ++r) {
        const int b = g8 + mrow + r, d = d0 + nt * 16 + lr;
        creg[nt][r] = load_c ? cf32[(size_t)b * DIM + d] : 0.0f;
        st_b16_sc(cgrp + (mrow + r) * DIM + d, f2b(creg[nt][r]));  // buffer 0
      }
    // prefetch step-0 gates
    const size_t base = (size_t)t * (BATCH * DIM);
    #pragma unroll
    for (int nt = 0; nt < 2; ++nt)
      #pragma unroll
      for (int r = 0; r < 4; ++r) {
        const size_t idx = base + (size_t)(g8 + mrow + r) * DIM + d0 + nt * 16 + lr;
        xi[nt][r] = b2f(XI[idx]); xf[nt][r] = b2f(XF[idx]);
        xc[nt][r] = b2f(XC[idx]); xv[nt][r] = b2f(Xb[idx]);
      }
  }

  u32 epoch = 1;
  g_arrive(gcnt);
  g_wait(gcnt, GWGS * epoch); ++epoch;

  for (int step = 0; step < L_SEQ; ++step, t += dt) {
    const size_t base = (size_t)t * (BATCH * DIM);
    const u16* crd = cgrp + (size_t)(step & 1) * (GROWS * DIM);
    u16* cwr = cgrp + (size_t)((step + 1) & 1) * (GROWS * DIM);

    // A fragments: row = lr (valid 0..7), k = w*256 + kk8*32 + q*8 + j.
    // Rows 8..15 of the 16x16 tile are zero (not loaded).
    uint4 afr[8];
    if (lr < 8) {
      const u64 ab = (u64)(uintptr_t)crd + (u32)(lr * 2048 + w * 512 + q * 16);
      asm volatile(
        "global_load_dwordx4 %0, %8, off sc0 sc1\n\t"
        "global_load_dwordx4 %1, %8, off offset:64 sc0 sc1\n\t"
        "global_load_dwordx4 %2, %8, off offset:128 sc0 sc1\n\t"
        "global_load_dwordx4 %3, %8, off offset:192 sc0 sc1\n\t"
        "global_load_dwordx4 %4, %8, off offset:256 sc0 sc1\n\t"
        "global_load_dwordx4 %5, %8, off offset:320 sc0 sc1\n\t"
        "global_load_dwordx4 %6, %8, off offset:384 sc0 sc1\n\t"
        "global_load_dwordx4 %7, %8, off offset:448 sc0 sc1\n\t"
        "s_waitcnt vmcnt(0)"
        : "=&v"(afr[0]), "=&v"(afr[1]), "=&v"(afr[2]), "=&v"(afr[3]),
          "=&v"(afr[4]), "=&v"(afr[5]), "=&v"(afr[6]), "=&v"(afr[7])
        : "v"(ab)
        : "memory");
    } else {
      #pragma unroll
      for (int i = 0; i < 8; ++i) afr[i] = (uint4){0, 0, 0, 0};
    }

    floatx4 acc[2][2];
    #pragma unroll
    for (int nt = 0; nt < 2; ++nt)
      #pragma unroll
      for (int g = 0; g < 2; ++g) acc[nt][g] = (floatx4){0, 0, 0, 0};
    #pragma unroll
    for (int kk8 = 0; kk8 < 8; ++kk8) {
      const short8 a = __builtin_bit_cast(short8, afr[kk8]);
      #pragma unroll
      for (int nt = 0; nt < 2; ++nt) {
        acc[nt][0] = __builtin_amdgcn_mfma_f32_16x16x32_bf16(a, bregs[kk8][nt][0], acc[nt][0], 0, 0, 0);
        acc[nt][1] = __builtin_amdgcn_mfma_f32_16x16x32_bf16(a, bregs[kk8][nt][1], acc[nt][1], 0, 0, 0);
      }
    }
    #pragma unroll
    for (int nt = 0; nt < 2; ++nt) {
      part[w][nt][0][l] = acc[nt][0];
      part[w][nt][1][l] = acc[nt][1];
    }
    __syncthreads();

    if (act) {
      floatx4 sI[2], sF[2];
      #pragma unroll
      for (int nt = 0; nt < 2; ++nt) {
        sI[nt] = part[0][nt][0][l]; sF[nt] = part[0][nt][1][l];
        #pragma unroll
        for (int pw = 1; pw < 4; ++pw) { sI[nt] += part[pw][nt][0][l]; sF[nt] += part[pw][nt][1][l]; }
      }
      #pragma unroll
      for (int nt = 0; nt < 2; ++nt)
        #pragma unroll
        for (int r = 0; r < 4; ++r) {
          const float iv = 1.0f / (1.0f + __expf(-(xi[nt][r] + sI[nt][r])));
          const float fv = 1.0f / (1.0f + __expf(-(xf[nt][r] + sF[nt][r])));
          const float cn = iv * xc[nt][r] + fv * creg[nt][r];
          creg[nt][r] = cn;
          const float hv = tanhf(cn) + xv[nt][r];
          const int d = d0 + nt * 16 + lr;
          const size_t idx = base + (size_t)(g8 + mrow + r) * DIM + d;
          __builtin_nontemporal_store(f2b(hv), Xb + idx);
          if (write_out) __builtin_nontemporal_store(hv, HoutF + idx);
          st_b16_sc(cwr + (mrow + r) * DIM + d, f2b(cn));
        }
    }
    g_arrive(gcnt);
    if (act && step + 1 < L_SEQ) {   // prefetch next gates during the wait
      const size_t nb = (size_t)(t + dt) * (BATCH * DIM);
      #pragma unroll
      for (int nt = 0; nt < 2; ++nt)
        #pragma unroll
        for (int r = 0; r < 4; ++r) {
          const size_t idx = nb + (size_t)(g8 + mrow + r) * DIM + d0 + nt * 16 + lr;
          xi[nt][r] = b2f(XI[idx]); xf[nt][r] = b2f(XF[idx]);
          xc[nt][r] = b2f(XC[idx]); xv[nt][r] = b2f(Xb[idx]);
        }
    }
    g_wait(gcnt, GWGS * epoch); ++epoch;
  }

  if (act) {
    #pragma unroll
    for (int nt = 0; nt < 2; ++nt)
      #pragma unroll
      for (int r = 0; r < 4; ++r)
        cf32[(size_t)(g8 + mrow + r) * DIM + d0 + nt * 16 + lr] = creg[nt][r];
  }
}

// -------- launcher ----------------------------------------------------------
extern "C" void kernel_launch(void* const* d_in, const int* in_sizes, int n_in,
                              void* d_out, int out_size, void* d_ws, size_t ws_size,
                              hipStream_t stream) {
  (void)in_sizes; (void)out_size; (void)ws_size;
  const int* xs = (const int*)d_in[0];
  const float* emb = (const float*)d_in[1];
  const float* W[18];
  for (int i = 0; i < 18 && i < n_in; ++i) W[i] = (const float*)d_in[i];

  char* ws = (char*)d_ws;
  u32* cnt    = (u32*)ws;                            // 4 KB counters (4 scans x 8 groups x 32)
  u16* WT     = (u16*)(ws + 8192);                   // 6 x [1024][1024] bf16
  u16* Xb     = (u16*)(ws + 12591104ull);            // [256][64][1024] bf16, in place
  u16* XIb    = (u16*)(ws + 46145536ull);
  u16* XFb    = (u16*)(ws + 79699968ull);
  u16* XCb    = (u16*)(ws + 113254400ull);
  u16* cbf    = (u16*)(ws + 146808832ull);           // [8][2][8][1024] bf16 = 256 KB
  float* cf32 = (float*)(ws + 147070976ull);         // [64][1024] fp32

  zero_cnt<<<1, 256, 0, stream>>>(cnt);
  transpose6<<<dim3(16, 16, 6), 256, 0, stream>>>(W[2], W[4], W[6], W[10], W[12], W[14], WT);
  embed_gather<<<16384, 256, 0, stream>>>(xs, emb, Xb);

  for (int s = 0; s < 4; ++s) {
    const int p = s & 1;   // 0 = forward(fw weights), 1 = reverse(bw weights)
    const u16* WTs = WT + (size_t)p * 3 * DIM * DIM;
    proj3<<<dim3(128, 8, 3), 256, 0, stream>>>(
        Xb, WTs, W[p ? 15 : 7], W[p ? 16 : 8], W[p ? 17 : 9], XIb, XFb, XCb);
    ran_scan_g<<<256, 256, 0, stream>>>(
        W[p ? 11 : 3], W[p ? 13 : 5], XIb, XFb, XCb, Xb, (float*)d_out,
        cbf, cf32, cnt + s * 256, p, s > 0 ? 1 : 0, s == 3 ? 1 : 0);
  }
}